// Round 6
// baseline (26.267 us; speedup 1.0000x reference)
//
#include <hip/hip_runtime.h>
#include <stdint.h>
#include <math.h>

#define NEAR_PLANE 0.0001f
#define MIN_COV    0.0001f
#define SIGMA_RAD  3.0f
#define ALPHA_MAX  0.999f

__device__ inline unsigned long long shflx64(unsigned long long v, int j) {
    int lo = __shfl_xor((int)(unsigned)(v & 0xFFFFFFFFull), j, 64);
    int hi = __shfl_xor((int)(unsigned)(v >> 32), j, 64);
    return ((unsigned long long)(unsigned)hi << 32) | (unsigned)lo;
}

// K1: per-gaussian projection.
// params (3 x float4): v0=(mx,my,ia,ib) v1=(ic,op,r,g) v2=(p01,p23,b,0)
//   p01/p23 = packed s16 bbox (minx,maxx),(miny,maxy); empty box if culled.
// zb: z float-bits (+inf if culled). bbox: packed s16 (for the cull pass).
__global__ __launch_bounds__(256) void gs_prep(
        const float* __restrict__ means,
        const float* __restrict__ covs,
        const float* __restrict__ colors,
        const float* __restrict__ opac,
        const float* __restrict__ K,
        const float* __restrict__ c2w,
        const int* __restrict__ hp, const int* __restrict__ wp,
        float4* __restrict__ params,
        unsigned* __restrict__ zb,
        uint2* __restrict__ bbox,
        int N) {
    int i = blockIdx.x * blockDim.x + threadIdx.x;
    if (i >= N) return;
    float Wf = (float)(*wp), Hf = (float)(*hp);

    float R[3][3];
    #pragma unroll
    for (int r = 0; r < 3; ++r)
        #pragma unroll
        for (int c = 0; c < 3; ++c)
            R[r][c] = c2w[c * 4 + r];
    float ct0 = c2w[3], ct1 = c2w[7], ct2 = c2w[11];
    float t0 = -(R[0][0]*ct0 + R[0][1]*ct1 + R[0][2]*ct2);
    float t1 = -(R[1][0]*ct0 + R[1][1]*ct1 + R[1][2]*ct2);
    float t2 = -(R[2][0]*ct0 + R[2][1]*ct1 + R[2][2]*ct2);

    float m0 = means[i*3+0], m1 = means[i*3+1], m2 = means[i*3+2];
    float x = R[0][0]*m0 + R[0][1]*m1 + R[0][2]*m2 + t0;
    float y = R[1][0]*m0 + R[1][1]*m1 + R[1][2]*m2 + t1;
    float z = R[2][0]*m0 + R[2][1]*m1 + R[2][2]*m2 + t2;

    const float* C = covs + i * 9;
    float M[3][3], CC[3][3];
    #pragma unroll
    for (int r = 0; r < 3; ++r)
        #pragma unroll
        for (int c = 0; c < 3; ++c)
            M[r][c] = R[r][0]*C[0*3+c] + R[r][1]*C[1*3+c] + R[r][2]*C[2*3+c];
    #pragma unroll
    for (int r = 0; r < 3; ++r)
        #pragma unroll
        for (int c = 0; c < 3; ++c)
            CC[r][c] = M[r][0]*R[c][0] + M[r][1]*R[c][1] + M[r][2]*R[c][2];

    bool vis = z > NEAR_PLANE;
    float sz = vis ? z : 1.0f;
    float fx = K[0], fy = K[4], cx = K[2], cy = K[5];
    float mx = fx * x / sz + cx;
    float my = fy * y / sz + cy;

    float a0 = fx / sz, a2 = -fx * x / (sz * sz);
    float b1 = fy / sz, b2 = -fy * y / (sz * sz);
    float u0 = a0*CC[0][0] + a2*CC[2][0];
    float u1 = a0*CC[0][1] + a2*CC[2][1];
    float u2 = a0*CC[0][2] + a2*CC[2][2];
    float v1 = b1*CC[1][1] + b2*CC[2][1];
    float v2 = b1*CC[1][2] + b2*CC[2][2];
    float a = u0*a0 + u2*a2 + MIN_COV;
    float b = u1*b1 + u2*b2;
    float c = v1*b1 + v2*b2 + MIN_COV;

    float disc = sqrtf(fmaxf((a - c)*(a - c) + 4.0f*b*b, 0.0f));
    float lam  = fmaxf(0.5f*(a + c + disc), MIN_COV);
    float rad  = SIGMA_RAD * sqrtf(lam);
    float minx = floorf(mx - rad), maxx = ceilf(mx + rad);
    float miny = floorf(my - rad), maxy = ceilf(my + rad);
    bool overlap = vis && (maxx >= 0.0f) && (minx < Wf) && (maxy >= 0.0f) && (miny < Hf);

    float det = fmaxf(a*c - b*b, 1e-12f);

    int mnx, mxx, mny, mxy;
    if (overlap) {
        mnx = (int)fmaxf(fminf(minx,  32767.0f), -32768.0f);
        mxx = (int)fmaxf(fminf(maxx,  32767.0f), -32768.0f);
        mny = (int)fmaxf(fminf(miny,  32767.0f), -32768.0f);
        mxy = (int)fmaxf(fminf(maxy,  32767.0f), -32768.0f);
    } else {
        mnx = 32767; mxx = -32768; mny = 32767; mxy = -32768;  // empty
    }
    unsigned p01 = (unsigned)(mnx & 0xFFFF) | ((unsigned)(mxx & 0xFFFF) << 16);
    unsigned p23 = (unsigned)(mny & 0xFFFF) | ((unsigned)(mxy & 0xFFFF) << 16);
    float op = overlap ? opac[i] : 0.0f;

    params[i*3+0] = make_float4(mx, my, c / det, -b / det);
    params[i*3+1] = make_float4(a / det, op, colors[i*3+0], colors[i*3+1]);
    params[i*3+2] = make_float4(__int_as_float((int)p01), __int_as_float((int)p23),
                                colors[i*3+2], 0.0f);
    zb[i] = overlap ? __float_as_uint(z) : 0x7F800000u;
    bbox[i] = make_uint2(p01, p23);
}

// K2: keys-only hybrid bitonic sort (1 block of N threads, N pow2 <= 1024).
// key = zbits<<32 | idx  -> perm = stable depth order.
__global__ __launch_bounds__(1024) void gs_sort(
        const unsigned* __restrict__ zb,
        int* __restrict__ perm, int N) {
    __shared__ unsigned long long sk[1024];
    int i = threadIdx.x;
    unsigned long long key = ((unsigned long long)zb[i] << 32) | (unsigned)i;
    for (int k = 2; k <= N; k <<= 1) {
        int j = k >> 1;
        for (; j >= 64; j >>= 1) {
            sk[i] = key;
            __syncthreads();
            unsigned long long p = sk[i ^ j];
            __syncthreads();
            bool tm = (((i & j) == 0) == ((i & k) == 0));
            key = (tm == (key < p)) ? key : p;
        }
        for (; j >= 1; j >>= 1) {
            unsigned long long p = shflx64(key, j);
            bool tm = (((i & j) == 0) == ((i & k) == 0));
            key = (tm == (key < p)) ? key : p;
        }
    }
    perm[i] = (int)(key & 0xFFFFFFFFull);
}

// K3: one block (256 thr) per 8x8 tile. Stable 4-wave compaction of the
// globally-sorted order (no per-tile sort), then 4-way depth-split
// compositing with in-LDS ordered merge. Survivor params read from L2
// (broadcast: all lanes same address).
__global__ __launch_bounds__(256) void gs_render(
        const float4* __restrict__ params,
        const uint2* __restrict__ bbox,
        const int* __restrict__ perm,
        int W, int H, int N,
        float* __restrict__ out) {
    __shared__ int s_surv[1024];
    __shared__ int s_wcnt[4];
    __shared__ float4 s_part[4][64];

    int tid = threadIdx.x;
    int lane = tid & 63, wv = tid >> 6;
    int tilesX = (W + 7) >> 3;
    int tile = blockIdx.x;
    int tx0 = (tile % tilesX) << 3, ty0 = (tile / tilesX) << 3;
    int txMax = tx0 + 7, tyMax = ty0 + 7;

    // ---- stable cull: iterate sorted positions, compact survivors ----
    int running = 0;
    for (int rr = 0; rr < N; rr += 256) {
        int i = rr + tid;
        bool keep = false;
        int g = 0;
        if (i < N) {
            g = perm[i];
            uint2 bb = bbox[g];
            int gmnx = ((int)bb.x << 16) >> 16, gmxx = (int)bb.x >> 16;
            int gmny = ((int)bb.y << 16) >> 16, gmxy = (int)bb.y >> 16;
            keep = (gmxx >= tx0) & (gmnx <= txMax) & (gmxy >= ty0) & (gmny <= tyMax);
        }
        unsigned long long m = __ballot(keep);
        if (lane == 0) s_wcnt[wv] = __popcll(m);
        __syncthreads();
        int base = running;
        #pragma unroll
        for (int w = 0; w < 4; ++w) {
            int cw = s_wcnt[w];
            if (w < wv) base += cw;
            running += cw;
        }
        if (keep) {
            int pos = __popcll(m & ((1ull << lane) - 1ull));
            s_surv[base + pos] = g;
        }
        __syncthreads();
    }
    int S = running;

    // ---- composite: wave wv owns contiguous depth quarter ----
    int per = (S + 3) >> 2;
    int lo = wv * per, hi = min(S, lo + per);
    int px = tx0 + (lane & 7), py = ty0 + (lane >> 3);
    float fpx = (float)px, fpy = (float)py;
    float T = 1.0f, accr = 0.0f, accg = 0.0f, accb = 0.0f;
    #pragma unroll 2
    for (int i = lo; i < hi; ++i) {
        int g = s_surv[i];
        float4 l0 = params[g*3+0];
        float4 l1 = params[g*3+1];
        float4 l2 = params[g*3+2];
        int b01 = __float_as_int(l2.x), b23 = __float_as_int(l2.y);
        bool inside = (px >= ((b01 << 16) >> 16)) & (px <= (b01 >> 16))
                    & (py >= ((b23 << 16) >> 16)) & (py <= (b23 >> 16));
        float dx = fpx - l0.x, dy = fpy - l0.y;
        float q = fmaf(l0.z * dx, dx, fmaf(2.0f * l0.w * dx, dy, l1.x * dy * dy));
        float w = __expf(-0.5f * q);
        float alpha = inside ? fminf(l1.y * w, ALPHA_MAX) : 0.0f;
        float at = alpha * T;
        accr = fmaf(at, l1.z, accr);
        accg = fmaf(at, l1.w, accg);
        accb = fmaf(at, l2.z, accb);
        T = T - at;
        if (__all(T < 1e-6f)) break;
    }
    s_part[wv][lane] = make_float4(accr, accg, accb, T);
    __syncthreads();

    if (wv == 0 && px < W && py < H) {
        float Tc = 1.0f, r = 0.0f, g = 0.0f, b = 0.0f;
        #pragma unroll
        for (int s = 0; s < 4; ++s) {
            float4 p = s_part[s][lane];
            r = fmaf(Tc, p.x, r);
            g = fmaf(Tc, p.y, g);
            b = fmaf(Tc, p.z, b);
            Tc *= p.w;
        }
        int pix = py * W + px;
        out[pix*3+0] = r;
        out[pix*3+1] = g;
        out[pix*3+2] = b;
    }
}

extern "C" void kernel_launch(void* const* d_in, const int* in_sizes, int n_in,
                              void* d_out, int out_size, void* d_ws, size_t ws_size,
                              hipStream_t stream) {
    const float* means  = (const float*)d_in[0];
    const float* covs   = (const float*)d_in[1];
    const float* colors = (const float*)d_in[2];
    const float* opac   = (const float*)d_in[3];
    const float* K      = (const float*)d_in[4];
    const float* c2w    = (const float*)d_in[5];
    const int*   hp     = (const int*)d_in[6];
    const int*   wp     = (const int*)d_in[7];

    int N = in_sizes[0] / 3;       // 1024 (power of two, <=1024: sort kernel)
    int npix = out_size / 3;
    int W = (int)(sqrt((double)npix) + 0.5);
    int H = npix / W;              // square image in this instance

    char* ws = (char*)d_ws;
    float4*   params = (float4*)ws;                          // N*48 B
    unsigned* zbp    = (unsigned*)(ws + (size_t)N * 48);     // N*4 B
    uint2*    bboxp  = (uint2*)(ws + (size_t)N * 52);        // N*8 B
    int*      perm   = (int*)(ws + (size_t)N * 60);          // N*4 B

    gs_prep<<<(N + 255) / 256, 256, 0, stream>>>(means, covs, colors, opac, K, c2w,
                                                 hp, wp, params, zbp, bboxp, N);
    gs_sort<<<1, N, 0, stream>>>(zbp, perm, N);

    int tilesX = (W + 7) / 8, tilesY = (H + 7) / 8;
    gs_render<<<tilesX * tilesY, 256, 0, stream>>>(params, bboxp, perm, W, H, N,
                                                   (float*)d_out);
}

// Round 7
// 20.457 us; speedup vs baseline: 1.2840x; 1.2840x over previous
//
#include <hip/hip_runtime.h>
#include <stdint.h>
#include <math.h>

#define NEAR_PLANE 0.0001f
#define MIN_COV    0.0001f
#define SIGMA_RAD  3.0f
#define ALPHA_MAX  0.999f

__device__ inline unsigned long long shflx64(unsigned long long v, int j) {
    int lo = __shfl_xor((int)(unsigned)(v & 0xFFFFFFFFull), j, 64);
    int hi = __shfl_xor((int)(unsigned)(v >> 32), j, 64);
    return ((unsigned long long)(unsigned)hi << 32) | (unsigned)lo;
}

// K1: per-gaussian projection.
// params (3 x float4): v0=(mx,my,ia,ib) v1=(ic,op,r,g) v2=(p01,p23,b,0)
//   p01/p23 = packed s16 bbox (minx,maxx),(miny,maxy); empty box if culled.
// zb: z float-bits (+inf if culled).
__global__ __launch_bounds__(256) void gs_prep(
        const float* __restrict__ means,
        const float* __restrict__ covs,
        const float* __restrict__ colors,
        const float* __restrict__ opac,
        const float* __restrict__ K,
        const float* __restrict__ c2w,
        const int* __restrict__ hp, const int* __restrict__ wp,
        float4* __restrict__ params,
        unsigned* __restrict__ zb,
        uint2* __restrict__ bbox,
        int N) {
    int i = blockIdx.x * blockDim.x + threadIdx.x;
    if (i >= N) return;
    float Wf = (float)(*wp), Hf = (float)(*hp);

    float R[3][3];
    #pragma unroll
    for (int r = 0; r < 3; ++r)
        #pragma unroll
        for (int c = 0; c < 3; ++c)
            R[r][c] = c2w[c * 4 + r];
    float ct0 = c2w[3], ct1 = c2w[7], ct2 = c2w[11];
    float t0 = -(R[0][0]*ct0 + R[0][1]*ct1 + R[0][2]*ct2);
    float t1 = -(R[1][0]*ct0 + R[1][1]*ct1 + R[1][2]*ct2);
    float t2 = -(R[2][0]*ct0 + R[2][1]*ct1 + R[2][2]*ct2);

    float m0 = means[i*3+0], m1 = means[i*3+1], m2 = means[i*3+2];
    float x = R[0][0]*m0 + R[0][1]*m1 + R[0][2]*m2 + t0;
    float y = R[1][0]*m0 + R[1][1]*m1 + R[1][2]*m2 + t1;
    float z = R[2][0]*m0 + R[2][1]*m1 + R[2][2]*m2 + t2;

    const float* C = covs + i * 9;
    float M[3][3], CC[3][3];
    #pragma unroll
    for (int r = 0; r < 3; ++r)
        #pragma unroll
        for (int c = 0; c < 3; ++c)
            M[r][c] = R[r][0]*C[0*3+c] + R[r][1]*C[1*3+c] + R[r][2]*C[2*3+c];
    #pragma unroll
    for (int r = 0; r < 3; ++r)
        #pragma unroll
        for (int c = 0; c < 3; ++c)
            CC[r][c] = M[r][0]*R[c][0] + M[r][1]*R[c][1] + M[r][2]*R[c][2];

    bool vis = z > NEAR_PLANE;
    float sz = vis ? z : 1.0f;
    float fx = K[0], fy = K[4], cx = K[2], cy = K[5];
    float mx = fx * x / sz + cx;
    float my = fy * y / sz + cy;

    float a0 = fx / sz, a2 = -fx * x / (sz * sz);
    float b1 = fy / sz, b2 = -fy * y / (sz * sz);
    float u0 = a0*CC[0][0] + a2*CC[2][0];
    float u1 = a0*CC[0][1] + a2*CC[2][1];
    float u2 = a0*CC[0][2] + a2*CC[2][2];
    float v1 = b1*CC[1][1] + b2*CC[2][1];
    float v2 = b1*CC[1][2] + b2*CC[2][2];
    float a = u0*a0 + u2*a2 + MIN_COV;
    float b = u1*b1 + u2*b2;
    float c = v1*b1 + v2*b2 + MIN_COV;

    float disc = sqrtf(fmaxf((a - c)*(a - c) + 4.0f*b*b, 0.0f));
    float lam  = fmaxf(0.5f*(a + c + disc), MIN_COV);
    float rad  = SIGMA_RAD * sqrtf(lam);
    float minx = floorf(mx - rad), maxx = ceilf(mx + rad);
    float miny = floorf(my - rad), maxy = ceilf(my + rad);
    bool overlap = vis && (maxx >= 0.0f) && (minx < Wf) && (maxy >= 0.0f) && (miny < Hf);

    float det = fmaxf(a*c - b*b, 1e-12f);

    int mnx, mxx, mny, mxy;
    if (overlap) {
        mnx = (int)fmaxf(fminf(minx,  32767.0f), -32768.0f);
        mxx = (int)fmaxf(fminf(maxx,  32767.0f), -32768.0f);
        mny = (int)fmaxf(fminf(miny,  32767.0f), -32768.0f);
        mxy = (int)fmaxf(fminf(maxy,  32767.0f), -32768.0f);
    } else {
        mnx = 32767; mxx = -32768; mny = 32767; mxy = -32768;  // empty
    }
    unsigned p01 = (unsigned)(mnx & 0xFFFF) | ((unsigned)(mxx & 0xFFFF) << 16);
    unsigned p23 = (unsigned)(mny & 0xFFFF) | ((unsigned)(mxy & 0xFFFF) << 16);
    float op = overlap ? opac[i] : 0.0f;

    params[i*3+0] = make_float4(mx, my, c / det, -b / det);
    params[i*3+1] = make_float4(a / det, op, colors[i*3+0], colors[i*3+1]);
    params[i*3+2] = make_float4(__int_as_float((int)p01), __int_as_float((int)p23),
                                colors[i*3+2], 0.0f);
    zb[i] = overlap ? __float_as_uint(z) : 0x7F800000u;
    bbox[i] = make_uint2(p01, p23);
}

// K2: one block (256 thr = 4 waves) per 8x8 tile.
// Phase 1: cull -> survivor keys (zbits<<32|idx) in sk (atomic compaction;
//          order canonicalized by the sort).
// Phase 2: register-resident bitonic sort (shfl j<64, 1 LDS stage j=64..128;
//          LDS-array fallback for >256 survivors).
// Phase 3: 4 waves composite 4 contiguous depth ranges; params read from L2
//          (all lanes same address -> broadcast); in-LDS ordered merge.
__global__ __launch_bounds__(256) void gs_render(
        const float4* __restrict__ params,
        const unsigned* __restrict__ zb,
        const uint2* __restrict__ bbox,
        int W, int H, int N,
        float* __restrict__ out) {
    __shared__ unsigned long long sk[1024];
    __shared__ float4 s_part[4][64];
    __shared__ int s_cnt;

    int tid = threadIdx.x;
    int lane = tid & 63, wv = tid >> 6;
    int tilesX = (W + 7) >> 3;
    int tile = blockIdx.x;
    int tx0 = (tile % tilesX) << 3, ty0 = (tile / tilesX) << 3;
    int txMax = tx0 + 7, tyMax = ty0 + 7;

    if (tid == 0) s_cnt = 0;
    __syncthreads();

    // ---- phase 1: cull ----
    for (int rr = 0; rr < N; rr += 256) {
        int i = rr + tid;
        bool keep = false;
        unsigned long long key = 0;
        if (i < N) {
            uint2 bb = bbox[i];
            int gmnx = ((int)bb.x << 16) >> 16, gmxx = (int)bb.x >> 16;
            int gmny = ((int)bb.y << 16) >> 16, gmxy = (int)bb.y >> 16;
            keep = (gmxx >= tx0) & (gmnx <= txMax) & (gmxy >= ty0) & (gmny <= tyMax);
            if (keep) key = ((unsigned long long)zb[i] << 32) | (unsigned)i;
        }
        unsigned long long m = __ballot(keep);
        int base = 0;
        if (lane == 0 && m) base = atomicAdd(&s_cnt, __popcll(m));
        base = __shfl(base, 0, 64);
        if (keep) {
            int pos = __popcll(m & ((1ull << lane) - 1ull));
            sk[base + pos] = key;
        }
    }
    __syncthreads();
    int S = s_cnt;

    int pad = 1;
    while (pad < S) pad <<= 1;

    // ---- phase 2: sort ----
    if (pad <= 256) {
        int v = tid;
        unsigned long long key = (v < S) ? sk[v] : ~0ull;
        for (int k = 2; k <= pad; k <<= 1) {
            for (int j = k >> 1; j > 0; j >>= 1) {
                if (j >= 64) {
                    if (v < pad) sk[v] = key;
                    __syncthreads();
                    unsigned long long p = (v < pad) ? sk[v ^ j] : 0;
                    __syncthreads();
                    if (v < pad) {
                        bool tm = (((v & j) == 0) == ((v & k) == 0));
                        key = (tm == (key < p)) ? key : p;
                    }
                } else {
                    unsigned long long p = shflx64(key, j);
                    bool tm = (((v & j) == 0) == ((v & k) == 0));
                    key = (tm == (key < p)) ? key : p;
                }
            }
        }
        if (v < pad) sk[v] = key;
        __syncthreads();
    } else {
        for (int i = S + tid; i < pad; i += 256) sk[i] = ~0ull;
        __syncthreads();
        for (int k = 2; k <= pad; k <<= 1) {
            for (int j = k >> 1; j > 0; j >>= 1) {
                for (int i = tid; i < pad; i += 256) {
                    int ixj = i ^ j;
                    if (ixj > i) {
                        unsigned long long A = sk[i], B = sk[ixj];
                        bool up = (i & k) == 0;
                        if ((A > B) == up) { sk[i] = B; sk[ixj] = A; }
                    }
                }
                __syncthreads();
            }
        }
    }

    // ---- phase 3: composite ----
    int per = (S + 3) >> 2;
    int lo = wv * per, hi = min(S, lo + per);
    int px = tx0 + (lane & 7), py = ty0 + (lane >> 3);
    float fpx = (float)px, fpy = (float)py;
    float T = 1.0f, accr = 0.0f, accg = 0.0f, accb = 0.0f;
    #pragma unroll 2
    for (int i = lo; i < hi; ++i) {
        int g = (int)(sk[i] & 0xFFFFFFFFull);
        float4 l0 = params[g*3+0];
        float4 l1 = params[g*3+1];
        float4 l2 = params[g*3+2];
        int b01 = __float_as_int(l2.x), b23 = __float_as_int(l2.y);
        bool inside = (px >= ((b01 << 16) >> 16)) & (px <= (b01 >> 16))
                    & (py >= ((b23 << 16) >> 16)) & (py <= (b23 >> 16));
        float dx = fpx - l0.x, dy = fpy - l0.y;
        float q = fmaf(l0.z * dx, dx, fmaf(2.0f * l0.w * dx, dy, l1.x * dy * dy));
        float w = __expf(-0.5f * q);
        float alpha = inside ? fminf(l1.y * w, ALPHA_MAX) : 0.0f;
        float at = alpha * T;
        accr = fmaf(at, l1.z, accr);
        accg = fmaf(at, l1.w, accg);
        accb = fmaf(at, l2.z, accb);
        T = T - at;
        if (__all(T < 1e-6f)) break;
    }
    s_part[wv][lane] = make_float4(accr, accg, accb, T);
    __syncthreads();

    if (wv == 0 && px < W && py < H) {
        float Tc = 1.0f, r = 0.0f, g = 0.0f, b = 0.0f;
        #pragma unroll
        for (int s = 0; s < 4; ++s) {
            float4 p = s_part[s][lane];
            r = fmaf(Tc, p.x, r);
            g = fmaf(Tc, p.y, g);
            b = fmaf(Tc, p.z, b);
            Tc *= p.w;
        }
        int pix = py * W + px;
        out[pix*3+0] = r;
        out[pix*3+1] = g;
        out[pix*3+2] = b;
    }
}

extern "C" void kernel_launch(void* const* d_in, const int* in_sizes, int n_in,
                              void* d_out, int out_size, void* d_ws, size_t ws_size,
                              hipStream_t stream) {
    const float* means  = (const float*)d_in[0];
    const float* covs   = (const float*)d_in[1];
    const float* colors = (const float*)d_in[2];
    const float* opac   = (const float*)d_in[3];
    const float* K      = (const float*)d_in[4];
    const float* c2w    = (const float*)d_in[5];
    const int*   hp     = (const int*)d_in[6];
    const int*   wp     = (const int*)d_in[7];

    int N = in_sizes[0] / 3;       // 1024
    int npix = out_size / 3;
    int W = (int)(sqrt((double)npix) + 0.5);
    int H = npix / W;              // square image in this instance

    char* ws = (char*)d_ws;
    float4*   params = (float4*)ws;                          // N*48 B
    unsigned* zbp    = (unsigned*)(ws + (size_t)N * 48);     // N*4 B
    uint2*    bboxp  = (uint2*)(ws + (size_t)N * 52);        // N*8 B

    gs_prep<<<(N + 255) / 256, 256, 0, stream>>>(means, covs, colors, opac, K, c2w,
                                                 hp, wp, params, zbp, bboxp, N);

    int tilesX = (W + 7) / 8, tilesY = (H + 7) / 8;
    gs_render<<<tilesX * tilesY, 256, 0, stream>>>(params, zbp, bboxp, W, H, N,
                                                   (float*)d_out);
}

// Round 8
// 20.397 us; speedup vs baseline: 1.2878x; 1.0030x over previous
//
#include <hip/hip_runtime.h>
#include <stdint.h>
#include <math.h>

#define NEAR_PLANE 0.0001f
#define MIN_COV    0.0001f
#define SIGMA_RAD  3.0f
#define ALPHA_MAX  0.999f

__device__ inline unsigned long long shflx64(unsigned long long v, int j) {
    int lo = __shfl_xor((int)(unsigned)(v & 0xFFFFFFFFull), j, 64);
    int hi = __shfl_xor((int)(unsigned)(v >> 32), j, 64);
    return ((unsigned long long)(unsigned)hi << 32) | (unsigned)lo;
}

// K1: per-gaussian projection.
// params (3 x float4): v0=(mx,my,ia,ib) v1=(ic,op,r,g) v2=(p01,p23,b,0)
// crec (uint4): (p01, p23, zbits, 0)  [single 16B cull record]
//   p01/p23 = packed s16 bbox (minx,maxx),(miny,maxy); empty box if culled;
//   zbits = float bits of z (+inf if culled).
__global__ __launch_bounds__(256) void gs_prep(
        const float* __restrict__ means,
        const float* __restrict__ covs,
        const float* __restrict__ colors,
        const float* __restrict__ opac,
        const float* __restrict__ K,
        const float* __restrict__ c2w,
        const int* __restrict__ hp, const int* __restrict__ wp,
        float4* __restrict__ params,
        uint4* __restrict__ crec,
        int N) {
    int i = blockIdx.x * blockDim.x + threadIdx.x;
    if (i >= N) return;
    float Wf = (float)(*wp), Hf = (float)(*hp);

    float R[3][3];
    #pragma unroll
    for (int r = 0; r < 3; ++r)
        #pragma unroll
        for (int c = 0; c < 3; ++c)
            R[r][c] = c2w[c * 4 + r];
    float ct0 = c2w[3], ct1 = c2w[7], ct2 = c2w[11];
    float t0 = -(R[0][0]*ct0 + R[0][1]*ct1 + R[0][2]*ct2);
    float t1 = -(R[1][0]*ct0 + R[1][1]*ct1 + R[1][2]*ct2);
    float t2 = -(R[2][0]*ct0 + R[2][1]*ct1 + R[2][2]*ct2);

    float m0 = means[i*3+0], m1 = means[i*3+1], m2 = means[i*3+2];
    float x = R[0][0]*m0 + R[0][1]*m1 + R[0][2]*m2 + t0;
    float y = R[1][0]*m0 + R[1][1]*m1 + R[1][2]*m2 + t1;
    float z = R[2][0]*m0 + R[2][1]*m1 + R[2][2]*m2 + t2;

    const float* C = covs + i * 9;
    float M[3][3], CC[3][3];
    #pragma unroll
    for (int r = 0; r < 3; ++r)
        #pragma unroll
        for (int c = 0; c < 3; ++c)
            M[r][c] = R[r][0]*C[0*3+c] + R[r][1]*C[1*3+c] + R[r][2]*C[2*3+c];
    #pragma unroll
    for (int r = 0; r < 3; ++r)
        #pragma unroll
        for (int c = 0; c < 3; ++c)
            CC[r][c] = M[r][0]*R[c][0] + M[r][1]*R[c][1] + M[r][2]*R[c][2];

    bool vis = z > NEAR_PLANE;
    float sz = vis ? z : 1.0f;
    float fx = K[0], fy = K[4], cx = K[2], cy = K[5];
    float mx = fx * x / sz + cx;
    float my = fy * y / sz + cy;

    float a0 = fx / sz, a2 = -fx * x / (sz * sz);
    float b1 = fy / sz, b2 = -fy * y / (sz * sz);
    float u0 = a0*CC[0][0] + a2*CC[2][0];
    float u1 = a0*CC[0][1] + a2*CC[2][1];
    float u2 = a0*CC[0][2] + a2*CC[2][2];
    float v1 = b1*CC[1][1] + b2*CC[2][1];
    float v2 = b1*CC[1][2] + b2*CC[2][2];
    float a = u0*a0 + u2*a2 + MIN_COV;
    float b = u1*b1 + u2*b2;
    float c = v1*b1 + v2*b2 + MIN_COV;

    float disc = sqrtf(fmaxf((a - c)*(a - c) + 4.0f*b*b, 0.0f));
    float lam  = fmaxf(0.5f*(a + c + disc), MIN_COV);
    float rad  = SIGMA_RAD * sqrtf(lam);
    float minx = floorf(mx - rad), maxx = ceilf(mx + rad);
    float miny = floorf(my - rad), maxy = ceilf(my + rad);
    bool overlap = vis && (maxx >= 0.0f) && (minx < Wf) && (maxy >= 0.0f) && (miny < Hf);

    float det = fmaxf(a*c - b*b, 1e-12f);

    int mnx, mxx, mny, mxy;
    if (overlap) {
        mnx = (int)fmaxf(fminf(minx,  32767.0f), -32768.0f);
        mxx = (int)fmaxf(fminf(maxx,  32767.0f), -32768.0f);
        mny = (int)fmaxf(fminf(miny,  32767.0f), -32768.0f);
        mxy = (int)fmaxf(fminf(maxy,  32767.0f), -32768.0f);
    } else {
        mnx = 32767; mxx = -32768; mny = 32767; mxy = -32768;  // empty
    }
    unsigned p01 = (unsigned)(mnx & 0xFFFF) | ((unsigned)(mxx & 0xFFFF) << 16);
    unsigned p23 = (unsigned)(mny & 0xFFFF) | ((unsigned)(mxy & 0xFFFF) << 16);
    float op = overlap ? opac[i] : 0.0f;

    params[i*3+0] = make_float4(mx, my, c / det, -b / det);
    params[i*3+1] = make_float4(a / det, op, colors[i*3+0], colors[i*3+1]);
    params[i*3+2] = make_float4(__int_as_float((int)p01), __int_as_float((int)p23),
                                colors[i*3+2], 0.0f);
    crec[i] = make_uint4(p01, p23, overlap ? __float_as_uint(z) : 0x7F800000u, 0u);
}

// K2: one block (256 thr = 4 waves) per 8x8 tile.
// Phase 1: cull via single-dwordx4 records -> survivor keys in sk.
// Phase 2: register-resident bitonic sort (shfl j<64, LDS stage j>=64);
//          survivor indices written to s_gi (b32 reads in composite).
// Phase 3: 4 waves composite 4 contiguous depth ranges; params via SCALAR
//          loads (wave-uniform index, readfirstlane); in-LDS ordered merge;
//          coalesced float4 output stores.
__global__ __launch_bounds__(256) void gs_render(
        const float4* __restrict__ params,
        const uint4* __restrict__ crec,
        int W, int H, int N,
        float* __restrict__ out) {
    __shared__ unsigned long long sk[1024];
    __shared__ int s_gi[1024];
    __shared__ float4 s_part[4][64];
    __shared__ float s_merged[192];
    __shared__ int s_cnt;

    int tid = threadIdx.x;
    int lane = tid & 63, wv = tid >> 6;
    int tilesX = (W + 7) >> 3;
    int tile = blockIdx.x;
    int tx0 = (tile % tilesX) << 3, ty0 = (tile / tilesX) << 3;
    int txMax = tx0 + 7, tyMax = ty0 + 7;

    if (tid == 0) s_cnt = 0;
    __syncthreads();

    // ---- phase 1: cull ----
    for (int rr = 0; rr < N; rr += 256) {
        int i = rr + tid;
        bool keep = false;
        unsigned long long key = 0;
        if (i < N) {
            uint4 cr = crec[i];
            int gmnx = ((int)cr.x << 16) >> 16, gmxx = (int)cr.x >> 16;
            int gmny = ((int)cr.y << 16) >> 16, gmxy = (int)cr.y >> 16;
            keep = (gmxx >= tx0) & (gmnx <= txMax) & (gmxy >= ty0) & (gmny <= tyMax);
            key = ((unsigned long long)cr.z << 32) | (unsigned)i;
        }
        unsigned long long m = __ballot(keep);
        int base = 0;
        if (lane == 0 && m) base = atomicAdd(&s_cnt, __popcll(m));
        base = __shfl(base, 0, 64);
        if (keep) {
            int pos = __popcll(m & ((1ull << lane) - 1ull));
            sk[base + pos] = key;
        }
    }
    __syncthreads();
    int S = s_cnt;

    int pad = 1;
    while (pad < S) pad <<= 1;

    // ---- phase 2: sort ----
    if (pad <= 256) {
        int v = tid;
        unsigned long long key = (v < S) ? sk[v] : ~0ull;
        for (int k = 2; k <= pad; k <<= 1) {
            for (int j = k >> 1; j > 0; j >>= 1) {
                if (j >= 64) {
                    if (v < pad) sk[v] = key;
                    __syncthreads();
                    unsigned long long p = (v < pad) ? sk[v ^ j] : 0;
                    __syncthreads();
                    if (v < pad) {
                        bool tm = (((v & j) == 0) == ((v & k) == 0));
                        key = (tm == (key < p)) ? key : p;
                    }
                } else {
                    unsigned long long p = shflx64(key, j);
                    bool tm = (((v & j) == 0) == ((v & k) == 0));
                    key = (tm == (key < p)) ? key : p;
                }
            }
        }
        if (v < pad) s_gi[v] = (int)(key & 0xFFFFFFFFull);
        __syncthreads();
    } else {
        for (int i = S + tid; i < pad; i += 256) sk[i] = ~0ull;
        __syncthreads();
        for (int k = 2; k <= pad; k <<= 1) {
            for (int j = k >> 1; j > 0; j >>= 1) {
                for (int i = tid; i < pad; i += 256) {
                    int ixj = i ^ j;
                    if (ixj > i) {
                        unsigned long long A = sk[i], B = sk[ixj];
                        bool up = (i & k) == 0;
                        if ((A > B) == up) { sk[i] = B; sk[ixj] = A; }
                    }
                }
                __syncthreads();
            }
        }
        for (int i = tid; i < pad; i += 256) s_gi[i] = (int)(sk[i] & 0xFFFFFFFFull);
        __syncthreads();
    }

    // ---- phase 3: composite ----
    int per = (S + 3) >> 2;
    int lo = wv * per, hi = min(S, lo + per);
    int px = tx0 + (lane & 7), py = ty0 + (lane >> 3);
    float fpx = (float)px, fpy = (float)py;
    float T = 1.0f, accr = 0.0f, accg = 0.0f, accb = 0.0f;
    #pragma unroll 2
    for (int i = lo; i < hi; ++i) {
        int g = __builtin_amdgcn_readfirstlane(s_gi[i]);
        const float4* pp = params + g * 3;
        float4 l0 = pp[0];
        float4 l1 = pp[1];
        float4 l2 = pp[2];
        int b01 = __float_as_int(l2.x), b23 = __float_as_int(l2.y);
        bool inside = (px >= ((b01 << 16) >> 16)) & (px <= (b01 >> 16))
                    & (py >= ((b23 << 16) >> 16)) & (py <= (b23 >> 16));
        float dx = fpx - l0.x, dy = fpy - l0.y;
        float q = fmaf(l0.z * dx, dx, fmaf(2.0f * l0.w * dx, dy, l1.x * dy * dy));
        float w = __expf(-0.5f * q);
        float alpha = inside ? fminf(l1.y * w, ALPHA_MAX) : 0.0f;
        float at = alpha * T;
        accr = fmaf(at, l1.z, accr);
        accg = fmaf(at, l1.w, accg);
        accb = fmaf(at, l2.z, accb);
        T = T - at;
        if (__all(T < 1e-6f)) break;
    }
    s_part[wv][lane] = make_float4(accr, accg, accb, T);
    __syncthreads();

    if (wv == 0) {
        float Tc = 1.0f, r = 0.0f, g = 0.0f, b = 0.0f;
        #pragma unroll
        for (int s = 0; s < 4; ++s) {
            float4 p = s_part[s][lane];
            r = fmaf(Tc, p.x, r);
            g = fmaf(Tc, p.y, g);
            b = fmaf(Tc, p.z, b);
            Tc *= p.w;
        }
        s_merged[lane * 3 + 0] = r;
        s_merged[lane * 3 + 1] = g;
        s_merged[lane * 3 + 2] = b;
        // coalesced output: 48 float4 stores cover the 8x8 tile (full tiles)
        if (tx0 + 8 <= W && ty0 + 8 <= H) {
            if (lane < 48) {
                int row = lane / 6, q4 = lane % 6;
                float4 v = *(const float4*)&s_merged[row * 24 + q4 * 4];
                *(float4*)&out[(size_t)(ty0 + row) * W * 3 + tx0 * 3 + q4 * 4] = v;
            }
        } else if (px < W && py < H) {
            int pix = py * W + px;
            out[pix*3+0] = r;
            out[pix*3+1] = g;
            out[pix*3+2] = b;
        }
    }
}

extern "C" void kernel_launch(void* const* d_in, const int* in_sizes, int n_in,
                              void* d_out, int out_size, void* d_ws, size_t ws_size,
                              hipStream_t stream) {
    const float* means  = (const float*)d_in[0];
    const float* covs   = (const float*)d_in[1];
    const float* colors = (const float*)d_in[2];
    const float* opac   = (const float*)d_in[3];
    const float* K      = (const float*)d_in[4];
    const float* c2w    = (const float*)d_in[5];
    const int*   hp     = (const int*)d_in[6];
    const int*   wp     = (const int*)d_in[7];

    int N = in_sizes[0] / 3;       // 1024
    int npix = out_size / 3;
    int W = (int)(sqrt((double)npix) + 0.5);
    int H = npix / W;              // square image in this instance

    char* ws = (char*)d_ws;
    float4* params = (float4*)ws;                        // N*48 B
    uint4*  crecp  = (uint4*)(ws + (size_t)N * 48);      // N*16 B

    gs_prep<<<(N + 255) / 256, 256, 0, stream>>>(means, covs, colors, opac, K, c2w,
                                                 hp, wp, params, crecp, N);

    int tilesX = (W + 7) / 8, tilesY = (H + 7) / 8;
    gs_render<<<tilesX * tilesY, 256, 0, stream>>>(params, crecp, W, H, N,
                                                   (float*)d_out);
}